// Round 5
// baseline (213.064 us; speedup 1.0000x reference)
//
#include <hip/hip_runtime.h>

typedef _Float16 f16x8 __attribute__((ext_vector_type(8)));
typedef float f32x4 __attribute__((ext_vector_type(4)));

#define T_DIM 2048
#define E_DIM 2048
#define D_DIM 128
#define NB 4
#define KSP_P 8    // proj K-splits (K=2048 -> 256 each)
#define KCH_P 256
#define KSP_A 8    // av K-splits (chunks of 256 over s)
#define KCH_A 256
#define CH2 64     // stats chunk = 64 t-rows (one wave's span)
#define NCH2 (T_DIM / CH2)  // 32
#define PH_SLOT (1u << 20)  // elements per partial slot (8192 x 128)

__device__ __forceinline__ void gll16(const void* g, void* l) {
  __builtin_amdgcn_global_load_lds(
      (const __attribute__((address_space(1))) unsigned int*)g,
      (__attribute__((address_space(3))) unsigned int*)l, 16, 0, 0);
}

__device__ __forceinline__ void merge_stat(float& m, float& l, float pm, float pl) {
  if (pm != -__builtin_inff()) {
    float nm = fmaxf(m, pm);
    l = l * __expf(m - nm) + pl * __expf(pm - nm);
    m = nm;
  }
}

// ---------------- W [E,D] fp32 -> WhT [D,E] fp16 (B^T layout), 3 matrices ----------------

__global__ void cvt_w(const float* __restrict__ Wq, const float* __restrict__ Wk,
                      const float* __restrict__ Wv, _Float16* __restrict__ WhT) {
  int idx = blockIdx.x * 256 + threadIdx.x;  // 0..262143
  int w = blockIdx.y;
  const float* W = (w == 0) ? Wq : ((w == 1) ? Wk : Wv);
  int e = idx & (E_DIM - 1), d = idx >> 11;
  WhT[(size_t)w * (D_DIM * E_DIM) + idx] = (_Float16)W[e * D_DIM + d];
}

// ---------------- projection GEMM: 256x128 tile, split-K x8 ----------------
// grid (32, 3, KSP_P). Partials (fp16) into slot ks*3+mat; slots 0-11 in Ph0,
// 12-23 in Ph1 (both regions dead during proj). mat2 stored pre-transposed.

__global__ __launch_bounds__(256, 2) void proj_gemm(
    const float* __restrict__ x, const _Float16* __restrict__ WhT,
    _Float16* __restrict__ Ph0, _Float16* __restrict__ Ph1) {
  __shared__ _Float16 As[256 * 32];
  __shared__ _Float16 Bs[128 * 32];
  const int tid = threadIdx.x, w = tid >> 6, lane = tid & 63;
  const int wr = w >> 1, wc = w & 1, quad = lane >> 4, l16 = lane & 15;
  const int t0 = blockIdx.x * 256;
  const int wsel = blockIdx.y, ks = blockIdx.z;
  const _Float16* B = WhT + (size_t)wsel * (D_DIM * E_DIM);
  const int srow = lane >> 2, scol = (lane & 3) * 8;
  const int arow = tid >> 2, acol = (tid & 3) * 8;
  f32x4 acc[8][4] = {};
  for (int k0 = ks * KCH_P; k0 < ks * KCH_P + KCH_P; k0 += 32) {
    __syncthreads();
    // A: 256x32 fp32 load + convert + LDS write (4 passes of 64 rows)
#pragma unroll
    for (int p = 0; p < 4; ++p) {
      int row = p * 64 + arow;
      const float* xp = x + (size_t)(t0 + row) * E_DIM + k0 + acol;
      f32x4 a0 = *(const f32x4*)xp;
      f32x4 a1 = *(const f32x4*)(xp + 4);
      f16x8 o;
#pragma unroll
      for (int e = 0; e < 4; ++e) { o[e] = (_Float16)a0[e]; o[e + 4] = (_Float16)a1[e]; }
      *(f16x8*)(As + row * 32 + acol) = o;
    }
    // B: 128x32 async direct-to-LDS
#pragma unroll
    for (int q = 0; q < 2; ++q) {
      int rbase = w * 32 + q * 16;
      gll16(B + (size_t)(rbase + srow) * E_DIM + k0 + scol, Bs + rbase * 32);
    }
    __syncthreads();
    f16x8 af[8], bf[4];
#pragma unroll
    for (int i = 0; i < 8; ++i)
      af[i] = *(const f16x8*)(As + (wr * 128 + i * 16 + l16) * 32 + quad * 8);
#pragma unroll
    for (int j = 0; j < 4; ++j)
      bf[j] = *(const f16x8*)(Bs + (wc * 64 + j * 16 + l16) * 32 + quad * 8);
#pragma unroll
    for (int i = 0; i < 8; ++i)
#pragma unroll
      for (int j = 0; j < 4; ++j)
        acc[i][j] = __builtin_amdgcn_mfma_f32_16x16x32_f16(af[i], bf[j], acc[i][j], 0, 0, 0);
  }
  const int slot = ks * 3 + wsel;
  _Float16* P = (slot < 12) ? (Ph0 + ((size_t)slot << 20))
                            : (Ph1 + ((size_t)(slot - 12) << 20));
#pragma unroll
  for (int i = 0; i < 8; ++i)
#pragma unroll
    for (int j = 0; j < 4; ++j) {
      int n = wc * 64 + j * 16 + l16;
#pragma unroll
      for (int r = 0; r < 4; ++r) {
        int t = t0 + wr * 128 + i * 16 + quad * 4 + r;
        _Float16 h = (_Float16)acc[i][j][r];
        if (wsel < 2) P[(size_t)t * D_DIM + n] = h;
        else P[((size_t)(t >> 11) * D_DIM + n) * T_DIM + (t & (T_DIM - 1))] = h;
      }
    }
}

// ---------------- reduce proj partials (8 slots) -> Qh, Kh, VT ----------------

__global__ void proj_reduce(const _Float16* __restrict__ Ph0,
                            const _Float16* __restrict__ Ph1,
                            _Float16* __restrict__ Qh,
                            _Float16* __restrict__ Kh, _Float16* __restrict__ VT) {
  size_t u = ((size_t)blockIdx.x * 256 + threadIdx.x) * 8;
  int mat = (int)(u >> 20);
  size_t rem = u & ((1u << 20) - 1);
  float s[8] = {};
#pragma unroll
  for (int ks = 0; ks < KSP_P; ++ks) {
    int slot = ks * 3 + mat;
    const _Float16* P = (slot < 12) ? (Ph0 + ((size_t)slot << 20))
                                    : (Ph1 + ((size_t)(slot - 12) << 20));
    f16x8 p = *(const f16x8*)(P + rem);
#pragma unroll
    for (int e = 0; e < 8; ++e) s[e] += (float)p[e];
  }
  f16x8 o;
#pragma unroll
  for (int e = 0; e < 8; ++e) o[e] = (_Float16)s[e];
  _Float16* dst = (mat == 0) ? Qh : ((mat == 1) ? Kh : VT);
  *(f16x8*)(dst + rem) = o;
}

// ---------------- S = Q K^T / sqrt(D) + fused per-column partial stats ----------------
// grid (136, 4): x = triangular (t,s) tile pair, y = batch.
// Epilogue: per-wave column stats over its 64 t-rows -> Pm/Pl chunk c = 2x+wr.

__global__ __launch_bounds__(256) void s_gemm(const _Float16* __restrict__ Qh,
                                              const _Float16* __restrict__ Kh,
                                              _Float16* __restrict__ S,
                                              float* __restrict__ Pm,
                                              float* __restrict__ Pl) {
  // triangular decode
  int idx = blockIdx.x;
  int xt = (int)((sqrtf(8.f * idx + 1.f) - 1.f) * 0.5f);
  while ((xt + 1) * (xt + 2) / 2 <= idx) ++xt;
  while (xt * (xt + 1) / 2 > idx) --xt;
  int yt = idx - xt * (xt + 1) / 2;
  __shared__ _Float16 As[128 * 32];
  __shared__ _Float16 Bs[128 * 32];
  const int tid = threadIdx.x, w = tid >> 6, lane = tid & 63;
  const int wr = w >> 1, wc = w & 1, quad = lane >> 4, l16 = lane & 15;
  const int t0 = xt * 128, s0 = yt * 128, b = blockIdx.y;
  const _Float16* A = Qh + (size_t)b * T_DIM * D_DIM;
  const _Float16* B = Kh + (size_t)b * T_DIM * D_DIM;
  const int srow = lane >> 2, scol = (lane & 3) * 8;
  f32x4 acc[4][4] = {};
  for (int k0 = 0; k0 < D_DIM; k0 += 32) {
    __syncthreads();
#pragma unroll
    for (int q = 0; q < 2; ++q) {
      int rbase = w * 32 + q * 16;
      gll16(A + (size_t)(t0 + rbase + srow) * D_DIM + k0 + scol, As + rbase * 32);
      gll16(B + (size_t)(s0 + rbase + srow) * D_DIM + k0 + scol, Bs + rbase * 32);
    }
    __syncthreads();
    f16x8 af[4], bf[4];
#pragma unroll
    for (int i = 0; i < 4; ++i)
      af[i] = *(const f16x8*)(As + (wr * 64 + i * 16 + l16) * 32 + quad * 8);
#pragma unroll
    for (int j = 0; j < 4; ++j)
      bf[j] = *(const f16x8*)(Bs + (wc * 64 + j * 16 + l16) * 32 + quad * 8);
#pragma unroll
    for (int i = 0; i < 4; ++i)
#pragma unroll
      for (int j = 0; j < 4; ++j)
        acc[i][j] = __builtin_amdgcn_mfma_f32_16x16x32_f16(af[i], bf[j], acc[i][j], 0, 0, 0);
  }
  _Float16* Sb = S + (size_t)b * T_DIM * T_DIM;
  const float scale = 0.08838834764831845f;  // 1/sqrt(128)
  const float NEG = -__builtin_inff();
#pragma unroll
  for (int j = 0; j < 4; ++j) {
    const int s = s0 + wc * 64 + j * 16 + l16;
    float m = NEG;
#pragma unroll
    for (int i = 0; i < 4; ++i)
#pragma unroll
      for (int r = 0; r < 4; ++r) {
        int t = t0 + wr * 64 + i * 16 + quad * 4 + r;
        float v = (s > t) ? NEG : acc[i][j][r] * scale;
        Sb[(size_t)t * T_DIM + s] = (_Float16)v;
        m = fmaxf(m, v);
      }
    float l = 0.f;
    if (m != NEG) {
#pragma unroll
      for (int i = 0; i < 4; ++i)
#pragma unroll
        for (int r = 0; r < 4; ++r) {
          int t = t0 + wr * 64 + i * 16 + quad * 4 + r;
          float v = (s > t) ? NEG : acc[i][j][r] * scale;
          l += __expf(v - m);  // exp(-inf - m) = 0
        }
    }
    // merge across quad dim (lanes xor 16, 32)
#pragma unroll
    for (int d = 16; d <= 32; d <<= 1) {
      float pm = __shfl_xor(m, d, 64);
      float pl = __shfl_xor(l, d, 64);
      merge_stat(m, l, pm, pl);
    }
    if (quad == 0) {
      int c = 2 * xt + wr;
      Pm[((size_t)c * NB + b) * T_DIM + s] = m;
      Pl[((size_t)c * NB + b) * T_DIM + s] = l;
    }
  }
}

// ---------------- combine partials, two-level: 32 chunks of 64 rows ----------------

__global__ __launch_bounds__(256) void comb_stats(const float* __restrict__ Pm,
                                                  const float* __restrict__ Pl,
                                                  float* __restrict__ M,
                                                  float* __restrict__ L) {
  __shared__ float sM[8][32];
  __shared__ float sL[8][32];
  const int g = threadIdx.x >> 5, sl = threadIdx.x & 31;
  const int c = blockIdx.x * 32 + sl;
  const int b = c >> 11, s = c & (T_DIM - 1);
  float m = -__builtin_inff(), l = 0.f;
#pragma unroll
  for (int k = 0; k < NCH2 / 8; ++k) {
    int ch = g * (NCH2 / 8) + k;
    if (ch >= (s >> 6)) {  // chunk intersects valid region (and is written)
      size_t idx = ((size_t)ch * NB + b) * T_DIM + s;
      merge_stat(m, l, Pm[idx], Pl[idx]);
    }
  }
  sM[g][sl] = m;
  sL[g][sl] = l;
  __syncthreads();
  if (threadIdx.x < 32) {
    const int c2 = blockIdx.x * 32 + threadIdx.x;
    float fm = -__builtin_inff(), fl = 0.f;
#pragma unroll
    for (int gg = 0; gg < 8; ++gg) merge_stat(fm, fl, sM[gg][threadIdx.x], sL[gg][threadIdx.x]);
    M[c2] = fm;
    L[c2] = 1.f / fl;
  }
}

// ---------------- Z = A V, split-K: grid (16, 4, KSP_A) ----------------

__global__ __launch_bounds__(256) void av_gemm(const _Float16* __restrict__ S,
                                               const _Float16* __restrict__ VT,
                                               const float* __restrict__ M,
                                               const float* __restrict__ L,
                                               float* __restrict__ Zp) {
  const int t0 = blockIdx.x * 128, b = blockIdx.y, ks = blockIdx.z;
  const int Kmax = t0 + 128;
  const int Kstart = ks * KCH_A;
  if (Kstart >= Kmax) return;
  const int Kend = (Kstart + KCH_A < Kmax) ? (Kstart + KCH_A) : Kmax;
  __shared__ _Float16 As[128 * 32];
  __shared__ _Float16 Bs[128 * 32];
  __shared__ float Ms[KCH_A];
  __shared__ float Ls[KCH_A];
  const int tid = threadIdx.x, w = tid >> 6, lane = tid & 63;
  const int wr = w >> 1, wc = w & 1, quad = lane >> 4, l16 = lane & 15;
  const _Float16* Sb = S + (size_t)b * T_DIM * T_DIM;
  const _Float16* Vb = VT + (size_t)b * D_DIM * T_DIM;
  for (int i = tid; i < Kend - Kstart; i += 256) {
    Ms[i] = M[b * T_DIM + Kstart + i];
    Ls[i] = L[b * T_DIM + Kstart + i];
  }
  const int srow = lane >> 2, scol = (lane & 3) * 8;
  f32x4 acc[4][4] = {};
  for (int k0 = Kstart; k0 < Kend; k0 += 32) {
    __syncthreads();
#pragma unroll
    for (int q = 0; q < 2; ++q) {
      // A tile: load S fp16, apply a = exp(s - m_col) * inv_l_col, write LDS
      int u = q * 256 + tid;
      int row = u >> 2, c8 = (u & 3) * 8;
      int sc = k0 + c8;
      f16x8 v = *(const f16x8*)(Sb + (size_t)(t0 + row) * T_DIM + sc);
      f16x8 o;
#pragma unroll
      for (int e = 0; e < 8; ++e) {
        int li = sc + e - Kstart;
        float a = __expf((float)v[e] - Ms[li]) * Ls[li];
        o[e] = (_Float16)a;
      }
      *(f16x8*)(As + row * 32 + c8) = o;
      // B tile: V^T rows (d-major), direct-to-LDS
      int rbase = w * 32 + q * 16;
      gll16(Vb + (size_t)(rbase + srow) * T_DIM + k0 + scol, Bs + rbase * 32);
    }
    __syncthreads();
    f16x8 af[4], bf[4];
#pragma unroll
    for (int i = 0; i < 4; ++i)
      af[i] = *(const f16x8*)(As + (wr * 64 + i * 16 + l16) * 32 + quad * 8);
#pragma unroll
    for (int j = 0; j < 4; ++j)
      bf[j] = *(const f16x8*)(Bs + (wc * 64 + j * 16 + l16) * 32 + quad * 8);
#pragma unroll
    for (int i = 0; i < 4; ++i)
#pragma unroll
      for (int j = 0; j < 4; ++j)
        acc[i][j] = __builtin_amdgcn_mfma_f32_16x16x32_f16(af[i], bf[j], acc[i][j], 0, 0, 0);
  }
  float* Zb = Zp + ((size_t)ks * NB + b) * T_DIM * D_DIM;
#pragma unroll
  for (int i = 0; i < 4; ++i)
#pragma unroll
    for (int j = 0; j < 4; ++j) {
      int n = wc * 64 + j * 16 + l16;
#pragma unroll
      for (int r = 0; r < 4; ++r) {
        int t = t0 + wr * 64 + i * 16 + quad * 4 + r;
        Zb[(size_t)t * D_DIM + n] = acc[i][j][r];
      }
    }
}

// ---------------- reduce Z partials -> output ----------------

__global__ void z_reduce(const float* __restrict__ Zp, float* __restrict__ Z) {
  size_t flat = ((size_t)blockIdx.x * 256 + threadIdx.x) * 4;
  int t = (int)((flat >> 7) & (T_DIM - 1));
  int ns = ((t >> 7) + 2) >> 1;  // ceil((x+1)/2), x = t/128
  f32x4 s = {};
  for (int ks = 0; ks < ns; ++ks) {
    f32x4 p = *(const f32x4*)(Zp + ((size_t)ks * NB * T_DIM * D_DIM) + flat);
    s += p;
  }
  *(f32x4*)(Z + flat) = s;
}

// ---------------- launch ----------------

extern "C" void kernel_launch(void* const* d_in, const int* in_sizes, int n_in,
                              void* d_out, int out_size, void* d_ws, size_t ws_size,
                              hipStream_t stream) {
  const float* x = (const float*)d_in[0];
  const float* Wq = (const float*)d_in[1];
  const float* Wk = (const float*)d_in[2];
  const float* Wv = (const float*)d_in[3];
  char* ws = (char*)d_ws;
  // workspace layout (~79 MB), aliasing:
  //  [0, 33.5MB): Ph0 (proj partial slots 0-11, 24MB) -> later Zp (33.5MB)
  //  [41.4MB, 74.9MB): Ph1 (slots 12-23, 24MB) -> later S (33.5MB)
  float* Zp = (float*)(ws);                                // 33,554,432 B
  _Float16* Ph0 = (_Float16*)(ws);                         // 25,165,824 B (alias Zp)
  _Float16* WhT = (_Float16*)(ws + 33554432);              //  1,572,864 B
  _Float16* Qh = (_Float16*)(ws + 35127296);               //  2,097,152 B
  _Float16* Kh = (_Float16*)(ws + 37224448);               //  2,097,152 B
  _Float16* VT = (_Float16*)(ws + 39321600);               //  2,097,152 B
  _Float16* S = (_Float16*)(ws + 41418752);                // 33,554,432 B
  _Float16* Ph1 = (_Float16*)(ws + 41418752);              // 25,165,824 B (alias S)
  float* M = (float*)(ws + 74973184);                      //     32,768 B
  float* L = (float*)(ws + 75005952);                      //     32,768 B
  float* Pm = (float*)(ws + 75038720);                     //  1,048,576 B
  float* Pl = (float*)(ws + 76087296);                     //  1,048,576 B
  float* Z = (float*)d_out;

  cvt_w<<<dim3(1024, 3), 256, 0, stream>>>(Wq, Wk, Wv, WhT);
  proj_gemm<<<dim3(32, 3, KSP_P), 256, 0, stream>>>(x, WhT, Ph0, Ph1);
  proj_reduce<<<1536, 256, 0, stream>>>(Ph0, Ph1, Qh, Kh, VT);
  s_gemm<<<dim3(136, 4), 256, 0, stream>>>(Qh, Kh, S, Pm, Pl);
  comb_stats<<<256, 256, 0, stream>>>(Pm, Pl, M, L);
  av_gemm<<<dim3(16, 4, KSP_A), 256, 0, stream>>>(S, VT, M, L, Zp);
  z_reduce<<<1024, 256, 0, stream>>>(Zp, Z);
}

// Round 6
// 201.962 us; speedup vs baseline: 1.0550x; 1.0550x over previous
//
#include <hip/hip_runtime.h>

typedef _Float16 f16x8 __attribute__((ext_vector_type(8)));
typedef _Float16 f16x4 __attribute__((ext_vector_type(4)));
typedef float f32x4 __attribute__((ext_vector_type(4)));

#define T_DIM 2048
#define E_DIM 2048
#define D_DIM 128
#define NB 4
#define KSP_P 4    // proj K-splits (K=2048 -> 512 each)
#define KCH_P 512
#define KSP_A 8    // av K-splits (chunks of 256 over s)
#define KCH_A 256
#define NCH2 32    // stats chunks of 64 t-rows

__device__ __forceinline__ void gll16(const void* g, void* l) {
  __builtin_amdgcn_global_load_lds(
      (const __attribute__((address_space(1))) unsigned int*)g,
      (__attribute__((address_space(3))) unsigned int*)l, 16, 0, 0);
}

__device__ __forceinline__ void merge_stat(float& m, float& l, float pm, float pl) {
  if (pm != -__builtin_inff()) {
    float nm = fmaxf(m, pm);
    l = l * __expf(m - nm) + pl * __expf(pm - nm);
    m = nm;
  }
}

// ---------------- W [E,D] fp32 -> WhT [D,E] fp16 (B^T layout), 3 matrices ----------------

__global__ void cvt_w(const float* __restrict__ Wq, const float* __restrict__ Wk,
                      const float* __restrict__ Wv, _Float16* __restrict__ WhT) {
  int idx = blockIdx.x * 256 + threadIdx.x;  // 0..262143
  int w = blockIdx.y;
  const float* W = (w == 0) ? Wq : ((w == 1) ? Wk : Wv);
  int e = idx & (E_DIM - 1), d = idx >> 11;
  WhT[(size_t)w * (D_DIM * E_DIM) + idx] = (_Float16)W[e * D_DIM + d];
}

// ---------------- projection GEMM: 128x128 tile, split-K x4, BK=64 ----------------
// A (x, fp32) loaded DIRECTLY global->VGPR->cvt per fragment (no LDS, no barrier dep).
// B (WhT) via global_load_lds into 2 BK=32 sub-tiles. grid (64, 3, KSP_P).
// Partials (fp16) into Ph[slot<<20], slot = ks*3+wsel; mat2 stored pre-transposed.

__global__ __launch_bounds__(256) void proj_gemm(
    const float* __restrict__ x, const _Float16* __restrict__ WhT,
    _Float16* __restrict__ Ph) {
  __shared__ _Float16 Bs[2][128 * 32];
  const int tid = threadIdx.x, w = tid >> 6, lane = tid & 63;
  const int wr = w >> 1, wc = w & 1, quad = lane >> 4, l16 = lane & 15;
  const int t0 = blockIdx.x * 128;
  const int wsel = blockIdx.y, ks = blockIdx.z;
  const _Float16* B = WhT + (size_t)wsel * (D_DIM * E_DIM);
  const int srow = lane >> 2, scol = (lane & 3) * 8;
  f32x4 acc[4][4] = {};
  for (int k0 = ks * KCH_P; k0 < ks * KCH_P + KCH_P; k0 += 64) {
    __syncthreads();
#pragma unroll
    for (int h = 0; h < 2; ++h)
#pragma unroll
      for (int q = 0; q < 2; ++q) {
        int rbase = w * 32 + q * 16;
        gll16(B + (size_t)(rbase + srow) * E_DIM + k0 + h * 32 + scol,
              Bs[h] + rbase * 32);
      }
    __syncthreads();
#pragma unroll
    for (int h = 0; h < 2; ++h) {
      f16x8 af[4], bf[4];
#pragma unroll
      for (int i = 0; i < 4; ++i) {
        const float* xp = x + (size_t)(t0 + wr * 64 + i * 16 + l16) * E_DIM +
                          k0 + h * 32 + quad * 8;
        f32x4 a0 = *(const f32x4*)xp;
        f32x4 a1 = *(const f32x4*)(xp + 4);
#pragma unroll
        for (int e = 0; e < 4; ++e) {
          af[i][e] = (_Float16)a0[e];
          af[i][e + 4] = (_Float16)a1[e];
        }
      }
#pragma unroll
      for (int j = 0; j < 4; ++j)
        bf[j] = *(const f16x8*)(Bs[h] + (wc * 64 + j * 16 + l16) * 32 + quad * 8);
#pragma unroll
      for (int i = 0; i < 4; ++i)
#pragma unroll
        for (int j = 0; j < 4; ++j)
          acc[i][j] = __builtin_amdgcn_mfma_f32_16x16x32_f16(af[i], bf[j], acc[i][j], 0, 0, 0);
    }
  }
  _Float16* P = Ph + ((size_t)(ks * 3 + wsel) << 20);
  if (wsel < 2) {
#pragma unroll
    for (int i = 0; i < 4; ++i)
#pragma unroll
      for (int j = 0; j < 4; ++j) {
        int n = wc * 64 + j * 16 + l16;
#pragma unroll
        for (int r = 0; r < 4; ++r) {
          int t = t0 + wr * 64 + i * 16 + quad * 4 + r;
          P[(size_t)t * D_DIM + n] = (_Float16)acc[i][j][r];
        }
      }
  } else {
    // V: pre-transposed partial, 4 consecutive t at fixed n -> f16x4 store
#pragma unroll
    for (int i = 0; i < 4; ++i)
#pragma unroll
      for (int j = 0; j < 4; ++j) {
        int n = wc * 64 + j * 16 + l16;
        int t = t0 + wr * 64 + i * 16 + quad * 4;
        f16x4 o;
#pragma unroll
        for (int r = 0; r < 4; ++r) o[r] = (_Float16)acc[i][j][r];
        *(f16x4*)(P + ((size_t)(t >> 11) * D_DIM + n) * T_DIM + (t & (T_DIM - 1))) = o;
      }
  }
}

// ---------------- reduce proj partials (4 slots) -> Qh, Kh, VT ----------------

__global__ void proj_reduce(const _Float16* __restrict__ Ph, _Float16* __restrict__ Qh,
                            _Float16* __restrict__ Kh, _Float16* __restrict__ VT) {
  size_t u = ((size_t)blockIdx.x * 256 + threadIdx.x) * 8;
  int mat = (int)(u >> 20);
  size_t rem = u & ((1u << 20) - 1);
  float s[8] = {};
#pragma unroll
  for (int ks = 0; ks < KSP_P; ++ks) {
    f16x8 p = *(const f16x8*)(Ph + ((size_t)(ks * 3 + mat) << 20) + rem);
#pragma unroll
    for (int e = 0; e < 8; ++e) s[e] += (float)p[e];
  }
  f16x8 o;
#pragma unroll
  for (int e = 0; e < 8; ++e) o[e] = (_Float16)s[e];
  _Float16* dst = (mat == 0) ? Qh : ((mat == 1) ? Kh : VT);
  *(f16x8*)(dst + rem) = o;
}

// ---------------- S = Q K^T / sqrt(D), single-barrier full-K + fused stats ----------------
// grid (136, 4): triangular (t,s) tile pair, y = batch. B staged once (4 BK=32
// sub-tiles, 32 KB); A direct global->VGPR; 64 MFMA straight; stats epilogue.

__global__ __launch_bounds__(256) void s_gemm(const _Float16* __restrict__ Qh,
                                              const _Float16* __restrict__ Kh,
                                              _Float16* __restrict__ S,
                                              float* __restrict__ Pm,
                                              float* __restrict__ Pl) {
  // triangular decode
  int idx = blockIdx.x;
  int xt = (int)((sqrtf(8.f * idx + 1.f) - 1.f) * 0.5f);
  while ((xt + 1) * (xt + 2) / 2 <= idx) ++xt;
  while (xt * (xt + 1) / 2 > idx) --xt;
  int yt = idx - xt * (xt + 1) / 2;
  __shared__ _Float16 Bs[4][128 * 32];
  const int tid = threadIdx.x, w = tid >> 6, lane = tid & 63;
  const int wr = w >> 1, wc = w & 1, quad = lane >> 4, l16 = lane & 15;
  const int t0 = xt * 128, s0 = yt * 128, b = blockIdx.y;
  const _Float16* A = Qh + (size_t)b * T_DIM * D_DIM;
  const _Float16* B = Kh + (size_t)b * T_DIM * D_DIM;
  const int srow = lane >> 2, scol = (lane & 3) * 8;
#pragma unroll
  for (int kq = 0; kq < 4; ++kq)
#pragma unroll
    for (int q = 0; q < 2; ++q) {
      int rbase = w * 32 + q * 16;
      gll16(B + (size_t)(s0 + rbase + srow) * D_DIM + kq * 32 + scol,
            Bs[kq] + rbase * 32);
    }
  __syncthreads();
  f32x4 acc[4][4] = {};
#pragma unroll
  for (int kq = 0; kq < 4; ++kq) {
    f16x8 af[4], bf[4];
#pragma unroll
    for (int i = 0; i < 4; ++i)
      af[i] = *(const f16x8*)(A + (size_t)(t0 + wr * 64 + i * 16 + l16) * D_DIM +
                              kq * 32 + quad * 8);
#pragma unroll
    for (int j = 0; j < 4; ++j)
      bf[j] = *(const f16x8*)(Bs[kq] + (wc * 64 + j * 16 + l16) * 32 + quad * 8);
#pragma unroll
    for (int i = 0; i < 4; ++i)
#pragma unroll
      for (int j = 0; j < 4; ++j)
        acc[i][j] = __builtin_amdgcn_mfma_f32_16x16x32_f16(af[i], bf[j], acc[i][j], 0, 0, 0);
  }
  _Float16* Sb = S + (size_t)b * T_DIM * T_DIM;
  const float scale = 0.08838834764831845f;  // 1/sqrt(128)
  const float NEG = -__builtin_inff();
#pragma unroll
  for (int j = 0; j < 4; ++j) {
    const int s = s0 + wc * 64 + j * 16 + l16;
    float m = NEG;
#pragma unroll
    for (int i = 0; i < 4; ++i)
#pragma unroll
      for (int r = 0; r < 4; ++r) {
        int t = t0 + wr * 64 + i * 16 + quad * 4 + r;
        float v = (s > t) ? NEG : acc[i][j][r] * scale;
        Sb[(size_t)t * T_DIM + s] = (_Float16)v;
        m = fmaxf(m, v);
      }
    float l = 0.f;
    if (m != NEG) {
#pragma unroll
      for (int i = 0; i < 4; ++i)
#pragma unroll
        for (int r = 0; r < 4; ++r) {
          int t = t0 + wr * 64 + i * 16 + quad * 4 + r;
          float v = (s > t) ? NEG : acc[i][j][r] * scale;
          l += __expf(v - m);  // exp(-inf - m) = 0
        }
    }
    // merge across quad dim (lanes xor 16, 32)
#pragma unroll
    for (int d = 16; d <= 32; d <<= 1) {
      float pm = __shfl_xor(m, d, 64);
      float pl = __shfl_xor(l, d, 64);
      merge_stat(m, l, pm, pl);
    }
    if (quad == 0) {
      int c = 2 * xt + wr;
      Pm[((size_t)c * NB + b) * T_DIM + s] = m;
      Pl[((size_t)c * NB + b) * T_DIM + s] = l;
    }
  }
}

// ---------------- combine partials, two-level: 32 chunks of 64 rows ----------------

__global__ __launch_bounds__(256) void comb_stats(const float* __restrict__ Pm,
                                                  const float* __restrict__ Pl,
                                                  float* __restrict__ M,
                                                  float* __restrict__ L) {
  __shared__ float sM[8][32];
  __shared__ float sL[8][32];
  const int g = threadIdx.x >> 5, sl = threadIdx.x & 31;
  const int c = blockIdx.x * 32 + sl;
  const int b = c >> 11, s = c & (T_DIM - 1);
  float m = -__builtin_inff(), l = 0.f;
#pragma unroll
  for (int k = 0; k < NCH2 / 8; ++k) {
    int ch = g * (NCH2 / 8) + k;
    if (ch >= (s >> 6)) {  // chunk intersects valid region (and is written)
      size_t idx = ((size_t)ch * NB + b) * T_DIM + s;
      merge_stat(m, l, Pm[idx], Pl[idx]);
    }
  }
  sM[g][sl] = m;
  sL[g][sl] = l;
  __syncthreads();
  if (threadIdx.x < 32) {
    const int c2 = blockIdx.x * 32 + threadIdx.x;
    float fm = -__builtin_inff(), fl = 0.f;
#pragma unroll
    for (int gg = 0; gg < 8; ++gg) merge_stat(fm, fl, sM[gg][threadIdx.x], sL[gg][threadIdx.x]);
    M[c2] = fm;
    L[c2] = 1.f / fl;
  }
}

// ---------------- Z = A V, split-K: grid (16, 4, KSP_A) ----------------

__global__ __launch_bounds__(256) void av_gemm(const _Float16* __restrict__ S,
                                               const _Float16* __restrict__ VT,
                                               const float* __restrict__ M,
                                               const float* __restrict__ L,
                                               float* __restrict__ Zp) {
  const int t0 = blockIdx.x * 128, b = blockIdx.y, ks = blockIdx.z;
  const int Kmax = t0 + 128;
  const int Kstart = ks * KCH_A;
  if (Kstart >= Kmax) return;
  const int Kend = (Kstart + KCH_A < Kmax) ? (Kstart + KCH_A) : Kmax;
  __shared__ _Float16 As[128 * 32];
  __shared__ _Float16 Bs[128 * 32];
  __shared__ float Ms[KCH_A];
  __shared__ float Ls[KCH_A];
  const int tid = threadIdx.x, w = tid >> 6, lane = tid & 63;
  const int wr = w >> 1, wc = w & 1, quad = lane >> 4, l16 = lane & 15;
  const _Float16* Sb = S + (size_t)b * T_DIM * T_DIM;
  const _Float16* Vb = VT + (size_t)b * D_DIM * T_DIM;
  for (int i = tid; i < Kend - Kstart; i += 256) {
    Ms[i] = M[b * T_DIM + Kstart + i];
    Ls[i] = L[b * T_DIM + Kstart + i];
  }
  const int srow = lane >> 2, scol = (lane & 3) * 8;
  f32x4 acc[4][4] = {};
  for (int k0 = Kstart; k0 < Kend; k0 += 32) {
    __syncthreads();
#pragma unroll
    for (int q = 0; q < 2; ++q) {
      // A tile: load S fp16, apply a = exp(s - m_col) * inv_l_col, write LDS
      int u = q * 256 + tid;
      int row = u >> 2, c8 = (u & 3) * 8;
      int sc = k0 + c8;
      f16x8 v = *(const f16x8*)(Sb + (size_t)(t0 + row) * T_DIM + sc);
      f16x8 o;
#pragma unroll
      for (int e = 0; e < 8; ++e) {
        int li = sc + e - Kstart;
        float a = __expf((float)v[e] - Ms[li]) * Ls[li];
        o[e] = (_Float16)a;
      }
      *(f16x8*)(As + row * 32 + c8) = o;
      // B tile: V^T rows (d-major), direct-to-LDS
      int rbase = w * 32 + q * 16;
      gll16(Vb + (size_t)(rbase + srow) * T_DIM + k0 + scol, Bs + rbase * 32);
    }
    __syncthreads();
    f16x8 af[4], bf[4];
#pragma unroll
    for (int i = 0; i < 4; ++i)
      af[i] = *(const f16x8*)(As + (wr * 64 + i * 16 + l16) * 32 + quad * 8);
#pragma unroll
    for (int j = 0; j < 4; ++j)
      bf[j] = *(const f16x8*)(Bs + (wc * 64 + j * 16 + l16) * 32 + quad * 8);
#pragma unroll
    for (int i = 0; i < 4; ++i)
#pragma unroll
      for (int j = 0; j < 4; ++j)
        acc[i][j] = __builtin_amdgcn_mfma_f32_16x16x32_f16(af[i], bf[j], acc[i][j], 0, 0, 0);
  }
  float* Zb = Zp + ((size_t)ks * NB + b) * T_DIM * D_DIM;
#pragma unroll
  for (int i = 0; i < 4; ++i)
#pragma unroll
    for (int j = 0; j < 4; ++j) {
      int n = wc * 64 + j * 16 + l16;
#pragma unroll
      for (int r = 0; r < 4; ++r) {
        int t = t0 + wr * 64 + i * 16 + quad * 4 + r;
        Zb[(size_t)t * D_DIM + n] = acc[i][j][r];
      }
    }
}

// ---------------- reduce Z partials -> output ----------------

__global__ void z_reduce(const float* __restrict__ Zp, float* __restrict__ Z) {
  size_t flat = ((size_t)blockIdx.x * 256 + threadIdx.x) * 4;
  int t = (int)((flat >> 7) & (T_DIM - 1));
  int ns = ((t >> 7) + 2) >> 1;  // ceil((x+1)/2), x = t/128
  f32x4 s = {};
  for (int ks = 0; ks < ns; ++ks) {
    f32x4 p = *(const f32x4*)(Zp + ((size_t)ks * NB * T_DIM * D_DIM) + flat);
    s += p;
  }
  *(f32x4*)(Z + flat) = s;
}

// ---------------- launch ----------------

extern "C" void kernel_launch(void* const* d_in, const int* in_sizes, int n_in,
                              void* d_out, int out_size, void* d_ws, size_t ws_size,
                              hipStream_t stream) {
  const float* x = (const float*)d_in[0];
  const float* Wq = (const float*)d_in[1];
  const float* Wk = (const float*)d_in[2];
  const float* Wv = (const float*)d_in[3];
  char* ws = (char*)d_ws;
  // workspace layout (~79 MB), aliasing:
  //  [0, 33.5MB): Zp (av partials; region idle during proj/s phases)
  //  [41.4MB, 74.9MB): Ph during proj; overwritten by S after proj_reduce
  float* Zp = (float*)(ws);                                // 33,554,432 B
  _Float16* WhT = (_Float16*)(ws + 33554432);              //  1,572,864 B
  _Float16* Qh = (_Float16*)(ws + 35127296);               //  2,097,152 B
  _Float16* Kh = (_Float16*)(ws + 37224448);               //  2,097,152 B
  _Float16* VT = (_Float16*)(ws + 39321600);               //  2,097,152 B
  _Float16* S = (_Float16*)(ws + 41418752);                // 33,554,432 B
  _Float16* Ph = (_Float16*)(ws + 41418752);               // 25,165,824 B (alias S)
  float* M = (float*)(ws + 74973184);                      //     32,768 B
  float* L = (float*)(ws + 75005952);                      //     32,768 B
  float* Pm = (float*)(ws + 75038720);                     //  1,048,576 B
  float* Pl = (float*)(ws + 76087296);                     //  1,048,576 B
  float* Z = (float*)d_out;

  cvt_w<<<dim3(1024, 3), 256, 0, stream>>>(Wq, Wk, Wv, WhT);
  proj_gemm<<<dim3(64, 3, KSP_P), 256, 0, stream>>>(x, WhT, Ph);
  proj_reduce<<<1536, 256, 0, stream>>>(Ph, Qh, Kh, VT);
  s_gemm<<<dim3(136, 4), 256, 0, stream>>>(Qh, Kh, S, Pm, Pl);
  comb_stats<<<256, 256, 0, stream>>>(Pm, Pl, M, L);
  av_gemm<<<dim3(16, 4, KSP_A), 256, 0, stream>>>(S, VT, M, L, Zp);
  z_reduce<<<1024, 256, 0, stream>>>(Zp, Z);
}

// Round 7
// 176.356 us; speedup vs baseline: 1.2081x; 1.1452x over previous
//
#include <hip/hip_runtime.h>

typedef _Float16 f16x8 __attribute__((ext_vector_type(8)));
typedef _Float16 f16x4 __attribute__((ext_vector_type(4)));
typedef float f32x4 __attribute__((ext_vector_type(4)));

#define T_DIM 2048
#define E_DIM 2048
#define D_DIM 128
#define NB 4
#define KSP_P 4    // proj K-splits (K=2048 -> 512 each)
#define KCH_P 512
#define KSP_A 8    // av K-splits (chunks of 256 over s)
#define KCH_A 256
#define NCH2 32    // stats chunks of 64 t-rows

__device__ __forceinline__ void gll16(const void* g, void* l) {
  __builtin_amdgcn_global_load_lds(
      (const __attribute__((address_space(1))) unsigned int*)g,
      (__attribute__((address_space(3))) unsigned int*)l, 16, 0, 0);
}

__device__ __forceinline__ void merge_stat(float& m, float& l, float pm, float pl) {
  if (pm != -__builtin_inff()) {
    float nm = fmaxf(m, pm);
    l = l * __expf(m - nm) + pl * __expf(pm - nm);
    m = nm;
  }
}

// ---------------- W [E,D] fp32 -> WhT [D,E] fp16 (B^T layout), 3 matrices ----------------

__global__ void cvt_w(const float* __restrict__ Wq, const float* __restrict__ Wk,
                      const float* __restrict__ Wv, _Float16* __restrict__ WhT) {
  int idx = blockIdx.x * 256 + threadIdx.x;  // 0..262143
  int w = blockIdx.y;
  const float* W = (w == 0) ? Wq : ((w == 1) ? Wk : Wv);
  int e = idx & (E_DIM - 1), d = idx >> 11;
  WhT[(size_t)w * (D_DIM * E_DIM) + idx] = (_Float16)W[e * D_DIM + d];
}

// ---------------- projection GEMM: 128x128 tile, split-K x4, BK=32 ----------------
// A (x, fp32) staged via async global_load_lds with 16B-seg XOR swizzle seg^(row&7)
// (conflict-free reads, 2-way); cvt fp32->fp16 on fragment read. B (WhT, fp16)
// staged with swizzle seg^((row>>1)&3). grid (64, 3, KSP_P).
// Partials (fp16) into Ph[slot<<20], slot = ks*3+wsel; mat2 stored pre-transposed.

__global__ __launch_bounds__(256) void proj_gemm(
    const float* __restrict__ x, const _Float16* __restrict__ WhT,
    _Float16* __restrict__ Ph) {
  __shared__ float Asw[128 * 32];     // 16 KB fp32, swizzled
  __shared__ _Float16 Bsw[128 * 32];  // 8 KB fp16, swizzled
  const int tid = threadIdx.x, w = tid >> 6, lane = tid & 63;
  const int wr = w >> 1, wc = w & 1, quad = lane >> 4, l16 = lane & 15;
  const int t0 = blockIdx.x * 128;
  const int wsel = blockIdx.y, ks = blockIdx.z;
  const _Float16* B = WhT + (size_t)wsel * (D_DIM * E_DIM);
  const int arow = tid >> 3, aseg = tid & 7;  // A staging: +32 rows per pass
  const int brow = tid >> 2, bseg = tid & 3;  // B staging: +64 rows per pass
  f32x4 acc[4][4] = {};
  for (int k0 = ks * KCH_P; k0 < ks * KCH_P + KCH_P; k0 += 32) {
    __syncthreads();
#pragma unroll
    for (int p = 0; p < 4; ++p) {
      int row = p * 32 + arow;
      int gseg = aseg ^ (row & 7);
      gll16(x + (size_t)(t0 + row) * E_DIM + k0 + gseg * 4,
            Asw + row * 32 + aseg * 4);
    }
#pragma unroll
    for (int p = 0; p < 2; ++p) {
      int row = p * 64 + brow;
      int gseg = bseg ^ ((row >> 1) & 3);
      gll16(B + (size_t)row * E_DIM + k0 + gseg * 8,
            Bsw + row * 32 + bseg * 8);
    }
    __syncthreads();
    f16x8 af[4], bf[4];
#pragma unroll
    for (int i = 0; i < 4; ++i) {
      int row = wr * 64 + i * 16 + l16;
      int s0 = (2 * quad) ^ (row & 7);
      int s1 = (2 * quad + 1) ^ (row & 7);
      f32x4 a0 = *(const f32x4*)(Asw + row * 32 + s0 * 4);
      f32x4 a1 = *(const f32x4*)(Asw + row * 32 + s1 * 4);
#pragma unroll
      for (int e = 0; e < 4; ++e) {
        af[i][e] = (_Float16)a0[e];
        af[i][e + 4] = (_Float16)a1[e];
      }
    }
#pragma unroll
    for (int j = 0; j < 4; ++j) {
      int row = wc * 64 + j * 16 + l16;
      int sg = quad ^ ((row >> 1) & 3);
      bf[j] = *(const f16x8*)(Bsw + row * 32 + sg * 8);
    }
#pragma unroll
    for (int i = 0; i < 4; ++i)
#pragma unroll
      for (int j = 0; j < 4; ++j)
        acc[i][j] = __builtin_amdgcn_mfma_f32_16x16x32_f16(af[i], bf[j], acc[i][j], 0, 0, 0);
  }
  _Float16* P = Ph + ((size_t)(ks * 3 + wsel) << 20);
  if (wsel < 2) {
#pragma unroll
    for (int i = 0; i < 4; ++i)
#pragma unroll
      for (int j = 0; j < 4; ++j) {
        int n = wc * 64 + j * 16 + l16;
#pragma unroll
        for (int r = 0; r < 4; ++r) {
          int t = t0 + wr * 64 + i * 16 + quad * 4 + r;
          P[(size_t)t * D_DIM + n] = (_Float16)acc[i][j][r];
        }
      }
  } else {
    // V: pre-transposed partial, 4 consecutive t at fixed n -> f16x4 store
#pragma unroll
    for (int i = 0; i < 4; ++i)
#pragma unroll
      for (int j = 0; j < 4; ++j) {
        int n = wc * 64 + j * 16 + l16;
        int t = t0 + wr * 64 + i * 16 + quad * 4;
        f16x4 o;
#pragma unroll
        for (int r = 0; r < 4; ++r) o[r] = (_Float16)acc[i][j][r];
        *(f16x4*)(P + ((size_t)(t >> 11) * D_DIM + n) * T_DIM + (t & (T_DIM - 1))) = o;
      }
  }
}

// ---------------- reduce proj partials (4 slots) -> Qh, Kh, VT ----------------

__global__ void proj_reduce(const _Float16* __restrict__ Ph, _Float16* __restrict__ Qh,
                            _Float16* __restrict__ Kh, _Float16* __restrict__ VT) {
  size_t u = ((size_t)blockIdx.x * 256 + threadIdx.x) * 8;
  int mat = (int)(u >> 20);
  size_t rem = u & ((1u << 20) - 1);
  float s[8] = {};
#pragma unroll
  for (int ks = 0; ks < KSP_P; ++ks) {
    f16x8 p = *(const f16x8*)(Ph + ((size_t)(ks * 3 + mat) << 20) + rem);
#pragma unroll
    for (int e = 0; e < 8; ++e) s[e] += (float)p[e];
  }
  f16x8 o;
#pragma unroll
  for (int e = 0; e < 8; ++e) o[e] = (_Float16)s[e];
  _Float16* dst = (mat == 0) ? Qh : ((mat == 1) ? Kh : VT);
  *(f16x8*)(dst + rem) = o;
}

// ---------------- S = Q K^T / sqrt(D), single-barrier full-K + fused stats ----------------
// grid (136, 4): triangular (t,s) tile pair, y = batch. B staged once (4 BK=32
// sub-tiles, swizzled); A direct global->VGPR; 64 MFMA straight; stats epilogue.

__global__ __launch_bounds__(256) void s_gemm(const _Float16* __restrict__ Qh,
                                              const _Float16* __restrict__ Kh,
                                              _Float16* __restrict__ S,
                                              float* __restrict__ Pm,
                                              float* __restrict__ Pl) {
  // triangular decode
  int idx = blockIdx.x;
  int xt = (int)((sqrtf(8.f * idx + 1.f) - 1.f) * 0.5f);
  while ((xt + 1) * (xt + 2) / 2 <= idx) ++xt;
  while (xt * (xt + 1) / 2 > idx) --xt;
  int yt = idx - xt * (xt + 1) / 2;
  __shared__ _Float16 Bs[4][128 * 32];
  const int tid = threadIdx.x, w = tid >> 6, lane = tid & 63;
  const int wr = w >> 1, wc = w & 1, quad = lane >> 4, l16 = lane & 15;
  const int t0 = xt * 128, s0 = yt * 128, b = blockIdx.y;
  const _Float16* A = Qh + (size_t)b * T_DIM * D_DIM;
  const _Float16* B = Kh + (size_t)b * T_DIM * D_DIM;
  const int srow = lane >> 2;
  const int swz = ((lane & 3) ^ ((srow >> 1) & 3)) * 8;  // source-col swizzle
#pragma unroll
  for (int kq = 0; kq < 4; ++kq)
#pragma unroll
    for (int q = 0; q < 2; ++q) {
      int rbase = w * 32 + q * 16;
      gll16(B + (size_t)(s0 + rbase + srow) * D_DIM + kq * 32 + swz,
            Bs[kq] + rbase * 32);
    }
  __syncthreads();
  f32x4 acc[4][4] = {};
  const int bsg = (quad ^ ((l16 >> 1) & 3)) * 8;
#pragma unroll
  for (int kq = 0; kq < 4; ++kq) {
    f16x8 af[4], bf[4];
#pragma unroll
    for (int i = 0; i < 4; ++i)
      af[i] = *(const f16x8*)(A + (size_t)(t0 + wr * 64 + i * 16 + l16) * D_DIM +
                              kq * 32 + quad * 8);
#pragma unroll
    for (int j = 0; j < 4; ++j)
      bf[j] = *(const f16x8*)(Bs[kq] + (wc * 64 + j * 16 + l16) * 32 + bsg);
#pragma unroll
    for (int i = 0; i < 4; ++i)
#pragma unroll
      for (int j = 0; j < 4; ++j)
        acc[i][j] = __builtin_amdgcn_mfma_f32_16x16x32_f16(af[i], bf[j], acc[i][j], 0, 0, 0);
  }
  _Float16* Sb = S + (size_t)b * T_DIM * T_DIM;
  const float scale = 0.08838834764831845f;  // 1/sqrt(128)
  const float NEG = -__builtin_inff();
#pragma unroll
  for (int j = 0; j < 4; ++j) {
    const int s = s0 + wc * 64 + j * 16 + l16;
    float m = NEG;
#pragma unroll
    for (int i = 0; i < 4; ++i)
#pragma unroll
      for (int r = 0; r < 4; ++r) {
        int t = t0 + wr * 64 + i * 16 + quad * 4 + r;
        float v = (s > t) ? NEG : acc[i][j][r] * scale;
        Sb[(size_t)t * T_DIM + s] = (_Float16)v;
        m = fmaxf(m, v);
      }
    float l = 0.f;
    if (m != NEG) {
#pragma unroll
      for (int i = 0; i < 4; ++i)
#pragma unroll
        for (int r = 0; r < 4; ++r) {
          int t = t0 + wr * 64 + i * 16 + quad * 4 + r;
          float v = (s > t) ? NEG : acc[i][j][r] * scale;
          l += __expf(v - m);  // exp(-inf - m) = 0
        }
    }
    // merge across quad dim (lanes xor 16, 32)
#pragma unroll
    for (int d = 16; d <= 32; d <<= 1) {
      float pm = __shfl_xor(m, d, 64);
      float pl = __shfl_xor(l, d, 64);
      merge_stat(m, l, pm, pl);
    }
    if (quad == 0) {
      int c = 2 * xt + wr;
      Pm[((size_t)c * NB + b) * T_DIM + s] = m;
      Pl[((size_t)c * NB + b) * T_DIM + s] = l;
    }
  }
}

// ---------------- combine partials, two-level: 32 chunks of 64 rows ----------------

__global__ __launch_bounds__(256) void comb_stats(const float* __restrict__ Pm,
                                                  const float* __restrict__ Pl,
                                                  float* __restrict__ M,
                                                  float* __restrict__ L) {
  __shared__ float sM[8][32];
  __shared__ float sL[8][32];
  const int g = threadIdx.x >> 5, sl = threadIdx.x & 31;
  const int c = blockIdx.x * 32 + sl;
  const int b = c >> 11, s = c & (T_DIM - 1);
  float m = -__builtin_inff(), l = 0.f;
#pragma unroll
  for (int k = 0; k < NCH2 / 8; ++k) {
    int ch = g * (NCH2 / 8) + k;
    if (ch >= (s >> 6)) {  // chunk intersects valid region (and is written)
      size_t idx = ((size_t)ch * NB + b) * T_DIM + s;
      merge_stat(m, l, Pm[idx], Pl[idx]);
    }
  }
  sM[g][sl] = m;
  sL[g][sl] = l;
  __syncthreads();
  if (threadIdx.x < 32) {
    const int c2 = blockIdx.x * 32 + threadIdx.x;
    float fm = -__builtin_inff(), fl = 0.f;
#pragma unroll
    for (int gg = 0; gg < 8; ++gg) merge_stat(fm, fl, sM[gg][threadIdx.x], sL[gg][threadIdx.x]);
    M[c2] = fm;
    L[c2] = 1.f / fl;
  }
}

// ---------------- Z = A V, split-K: grid (16, 4, KSP_A) ----------------

__global__ __launch_bounds__(256) void av_gemm(const _Float16* __restrict__ S,
                                               const _Float16* __restrict__ VT,
                                               const float* __restrict__ M,
                                               const float* __restrict__ L,
                                               float* __restrict__ Zp) {
  const int t0 = blockIdx.x * 128, b = blockIdx.y, ks = blockIdx.z;
  const int Kmax = t0 + 128;
  const int Kstart = ks * KCH_A;
  if (Kstart >= Kmax) return;
  const int Kend = (Kstart + KCH_A < Kmax) ? (Kstart + KCH_A) : Kmax;
  __shared__ _Float16 As[128 * 32];
  __shared__ _Float16 Bs[128 * 32];
  __shared__ float Ms[KCH_A];
  __shared__ float Ls[KCH_A];
  const int tid = threadIdx.x, w = tid >> 6, lane = tid & 63;
  const int wr = w >> 1, wc = w & 1, quad = lane >> 4, l16 = lane & 15;
  const _Float16* Sb = S + (size_t)b * T_DIM * T_DIM;
  const _Float16* Vb = VT + (size_t)b * D_DIM * T_DIM;
  for (int i = tid; i < Kend - Kstart; i += 256) {
    Ms[i] = M[b * T_DIM + Kstart + i];
    Ls[i] = L[b * T_DIM + Kstart + i];
  }
  const int srow = lane >> 2, scol = (lane & 3) * 8;
  f32x4 acc[4][4] = {};
  for (int k0 = Kstart; k0 < Kend; k0 += 32) {
    __syncthreads();
#pragma unroll
    for (int q = 0; q < 2; ++q) {
      // A tile: load S fp16, apply a = exp(s - m_col) * inv_l_col, write LDS
      int u = q * 256 + tid;
      int row = u >> 2, c8 = (u & 3) * 8;
      int sc = k0 + c8;
      f16x8 v = *(const f16x8*)(Sb + (size_t)(t0 + row) * T_DIM + sc);
      f16x8 o;
#pragma unroll
      for (int e = 0; e < 8; ++e) {
        int li = sc + e - Kstart;
        float a = __expf((float)v[e] - Ms[li]) * Ls[li];
        o[e] = (_Float16)a;
      }
      *(f16x8*)(As + row * 32 + c8) = o;
      // B tile: V^T rows (d-major), direct-to-LDS
      int rbase = w * 32 + q * 16;
      gll16(Vb + (size_t)(rbase + srow) * T_DIM + k0 + scol, Bs + rbase * 32);
    }
    __syncthreads();
    f16x8 af[4], bf[4];
#pragma unroll
    for (int i = 0; i < 4; ++i)
      af[i] = *(const f16x8*)(As + (wr * 64 + i * 16 + l16) * 32 + quad * 8);
#pragma unroll
    for (int j = 0; j < 4; ++j)
      bf[j] = *(const f16x8*)(Bs + (wc * 64 + j * 16 + l16) * 32 + quad * 8);
#pragma unroll
    for (int i = 0; i < 4; ++i)
#pragma unroll
      for (int j = 0; j < 4; ++j)
        acc[i][j] = __builtin_amdgcn_mfma_f32_16x16x32_f16(af[i], bf[j], acc[i][j], 0, 0, 0);
  }
  float* Zb = Zp + ((size_t)ks * NB + b) * T_DIM * D_DIM;
#pragma unroll
  for (int i = 0; i < 4; ++i)
#pragma unroll
    for (int j = 0; j < 4; ++j) {
      int n = wc * 64 + j * 16 + l16;
#pragma unroll
      for (int r = 0; r < 4; ++r) {
        int t = t0 + wr * 64 + i * 16 + quad * 4 + r;
        Zb[(size_t)t * D_DIM + n] = acc[i][j][r];
      }
    }
}

// ---------------- reduce Z partials -> output ----------------

__global__ void z_reduce(const float* __restrict__ Zp, float* __restrict__ Z) {
  size_t flat = ((size_t)blockIdx.x * 256 + threadIdx.x) * 4;
  int t = (int)((flat >> 7) & (T_DIM - 1));
  int ns = ((t >> 7) + 2) >> 1;  // ceil((x+1)/2), x = t/128
  f32x4 s = {};
  for (int ks = 0; ks < ns; ++ks) {
    f32x4 p = *(const f32x4*)(Zp + ((size_t)ks * NB * T_DIM * D_DIM) + flat);
    s += p;
  }
  *(f32x4*)(Z + flat) = s;
}

// ---------------- launch ----------------

extern "C" void kernel_launch(void* const* d_in, const int* in_sizes, int n_in,
                              void* d_out, int out_size, void* d_ws, size_t ws_size,
                              hipStream_t stream) {
  const float* x = (const float*)d_in[0];
  const float* Wq = (const float*)d_in[1];
  const float* Wk = (const float*)d_in[2];
  const float* Wv = (const float*)d_in[3];
  char* ws = (char*)d_ws;
  // workspace layout (~79 MB), aliasing:
  //  [0, 33.5MB): Zp (av partials; region idle during proj/s phases)
  //  [41.4MB, 74.9MB): Ph during proj; overwritten by S after proj_reduce
  float* Zp = (float*)(ws);                                // 33,554,432 B
  _Float16* WhT = (_Float16*)(ws + 33554432);              //  1,572,864 B
  _Float16* Qh = (_Float16*)(ws + 35127296);               //  2,097,152 B
  _Float16* Kh = (_Float16*)(ws + 37224448);               //  2,097,152 B
  _Float16* VT = (_Float16*)(ws + 39321600);               //  2,097,152 B
  _Float16* S = (_Float16*)(ws + 41418752);                // 33,554,432 B
  _Float16* Ph = (_Float16*)(ws + 41418752);               // 25,165,824 B (alias S)
  float* M = (float*)(ws + 74973184);                      //     32,768 B
  float* L = (float*)(ws + 75005952);                      //     32,768 B
  float* Pm = (float*)(ws + 75038720);                     //  1,048,576 B
  float* Pl = (float*)(ws + 76087296);                     //  1,048,576 B
  float* Z = (float*)d_out;

  cvt_w<<<dim3(1024, 3), 256, 0, stream>>>(Wq, Wk, Wv, WhT);
  proj_gemm<<<dim3(64, 3, KSP_P), 256, 0, stream>>>(x, WhT, Ph);
  proj_reduce<<<1536, 256, 0, stream>>>(Ph, Qh, Kh, VT);
  s_gemm<<<dim3(136, 4), 256, 0, stream>>>(Qh, Kh, S, Pm, Pl);
  comb_stats<<<256, 256, 0, stream>>>(Pm, Pl, M, L);
  av_gemm<<<dim3(16, 4, KSP_A), 256, 0, stream>>>(S, VT, M, L, Zp);
  z_reduce<<<1024, 256, 0, stream>>>(Zp, Z);
}